// Round 17
// baseline (77.469 us; speedup 1.0000x reference)
//
#include <hip/hip_runtime.h>

#define ROWS 2
#define N 4096
#define BATCH 8192
#define S_AB 264            // arena row stride (floats): 256+8
#define ARENA 4224          // floats per arena (16*264); 2 arenas = 33792 B
#define NWS_F4 (8 * 2048)   // permuted f32 twiddles, layers 4..11

typedef float v4f __attribute__((ext_vector_type(4)));

// Half-layer butterfly: pcs [pcb, pcb+4) with twiddles in s[0..3] (R8-verified).
__device__ __forceinline__ void half_layer(float (&v)[ROWS][16],
                                           const float4 (&s)[4],
                                           const int bit, const int pcb) {
    const int d = 1 << bit;
    #pragma unroll
    for (int i = 0; i < 4; ++i) {
        const int pc = pcb + i;
        const int lo = ((pc >> bit) << (bit + 1)) | (pc & (d - 1));
        const int hi = lo + d;
        #pragma unroll
        for (int r = 0; r < ROWS; ++r) {
            const float top = v[r][lo], bot = v[r][hi];
            v[r][lo] = s[i].x * top + s[i].y * bot;
            v[r][hi] = s[i].z * top + s[i].w * bot;
        }
    }
}

// ---- Prepass (unchanged, f32): layers 4..11 -> lane-coalesced nws.
__global__ __launch_bounds__(256)
void permute_tw_kernel(const float* __restrict__ tw, float4* __restrict__ nws) {
    const int i = blockIdx.x * 256 + threadIdx.x;   // 0 .. 16383
    const int s  = i >> 11;                         // slot 0..7 -> layer 4+s
    const int j  = i & 2047;
    const int pc = j >> 8;
    const int a  = (j >> 4) & 15;
    const int cb = j & 15;
    const float4* tw4 = (const float4*)tw;
    const int src = (s < 4) ? (a * 128 + pc * 16 + cb)   // stage B layers 4..7
                            : (a * 128 + cb * 8 + pc);   // stage C layers 8..11
    nws[i] = tw4[(4 + s) * 2048 + src];
}

// ROWS=2 high-TLP probe on the R16 structure. Live state engineered <= 64
// VGPR (32 data + 16 half-layer twiddles + temps) to land in the 8-waves/SIMD
// bucket (empirical: 40 VGPR -> 50% occ in R10; 80-84 -> 28%; waves step at
// 64/128). launch_bounds(256,4) caps at exactly 64 (R5 law) — safe now that
// live fits. Trade: per-row twiddle VMEM doubles; this is the falsifier.
__global__ __launch_bounds__(256, 4)
void butterfly_kernel(const float* __restrict__ x,
                      const float* __restrict__ tw,
                      const float4* __restrict__ nws,
                      float* __restrict__ out) {
    __shared__ float lds[2 * ARENA];
    float* bufA = lds;
    float* bufB = lds + ARENA;
    const int t   = threadIdx.x;
    const int thi = t >> 4;
    const int tlo = t & 15;
    const int row0 = blockIdx.x * ROWS;
    const float4* tw4 = (const float4*)tw;

    auto ldA = [&](int l, int pcb, float4 (&s)[4]) {     // stage A natural (coalesced)
        #pragma unroll
        for (int i = 0; i < 4; ++i) s[i] = tw4[l * 2048 + (pcb + i) * 256 + t];
    };
    auto ldN = [&](int l, int pcb, float4 (&s)[4]) {     // layers 4..11 via nws
        #pragma unroll
        for (int i = 0; i < 4; ++i) s[i] = nws[(l - 4) * 2048 + (pcb + i) * 256 + t];
    };

    float v[ROWS][16];
    float4 S[4];

    // ---- Stage-in: rows 0/1 via dwordx4 through linear LDS (one batch).
    {
        const float* r0 = x + (size_t)(row0 + 0) * N + 4 * t;
        const float* r1 = x + (size_t)(row0 + 1) * N + 4 * t;
        v4f t0[4], t1[4];
        #pragma unroll
        for (int i = 0; i < 4; ++i) t0[i] = *(const v4f*)(r0 + i * 1024);
        #pragma unroll
        for (int i = 0; i < 4; ++i) t1[i] = *(const v4f*)(r1 + i * 1024);
        #pragma unroll
        for (int i = 0; i < 4; ++i) *(v4f*)(bufA + i * 1024 + 4 * t) = t0[i];
        #pragma unroll
        for (int i = 0; i < 4; ++i) *(v4f*)(bufB + i * 1024 + 4 * t) = t1[i];
        __syncthreads();
        #pragma unroll
        for (int a = 0; a < 16; ++a) v[0][a] = bufA[a * 256 + t];   // stride-1: free
        #pragma unroll
        for (int a = 0; a < 16; ++a) v[1][a] = bufB[a * 256 + t];
    }

    // ---- Stage A: layers 0..3 (pairs in a); sequential half-layer loads
    #pragma unroll
    for (int l = 0; l < 4; ++l) {
        ldA(l, 0, S); half_layer(v, S, 3 - l, 0);
        ldA(l, 4, S); half_layer(v, S, 3 - l, 4);
    }

    // ---- Transpose A->B (write stride-1, read 2-way: free)
    __syncthreads();                                // stage-in reads complete
    #pragma unroll
    for (int a = 0; a < 16; ++a) bufA[a * S_AB + t] = v[0][a];
    #pragma unroll
    for (int a = 0; a < 16; ++a) bufB[a * S_AB + t] = v[1][a];
    __syncthreads();
    #pragma unroll
    for (int b = 0; b < 16; ++b) v[0][b] = bufA[thi * S_AB + b * 16 + tlo];
    #pragma unroll
    for (int b = 0; b < 16; ++b) v[1][b] = bufB[thi * S_AB + b * 16 + tlo];

    // ---- Stage B: layers 4..7 (pairs in b); coalesced permuted twiddles
    #pragma unroll
    for (int l = 4; l < 8; ++l) {
        ldN(l, 0, S); half_layer(v, S, 3 - (l - 4), 0);
        ldN(l, 4, S); half_layer(v, S, 3 - (l - 4), 4);
    }

    // ---- Transpose B->C, compact q-XOR layout (R12-proven): elem (a,b,c) at
    // a*264 + b*16 + 4*((c>>2)^(b&3)) + (c&3).
    __syncthreads();                                // T_AB reads done
    #pragma unroll
    for (int b = 0; b < 16; ++b) {
        const int coff = 4 * (((tlo >> 2) ^ (b & 3))) + (tlo & 3);
        bufA[thi * S_AB + b * 16 + coff] = v[0][b];
        bufB[thi * S_AB + b * 16 + coff] = v[1][b];
    }
    __syncthreads();
    #pragma unroll
    for (int rr = 0; rr < 2; ++rr) {
        const float* bp = (rr ? bufB : bufA) + thi * S_AB + tlo * 16;
        #pragma unroll
        for (int q = 0; q < 4; ++q) {
            v4f c4 = *(const v4f*)(bp + 4 * (q ^ (tlo & 3)));
            v[rr][4 * q + 0] = c4.x; v[rr][4 * q + 1] = c4.y;
            v[rr][4 * q + 2] = c4.z; v[rr][4 * q + 3] = c4.w;
        }
    }

    // ---- Stage C: layers 8..11 (pairs in c)
    #pragma unroll
    for (int l = 8; l < 12; ++l) {
        ldN(l, 0, S); half_layer(v, S, 3 - (l - 8), 0);
        ldN(l, 4, S); half_layer(v, S, 3 - (l - 8), 4);
    }

    // ---- Store restage (load-bearing, R14): XOR layout, one 2-row batch,
    // then 1KB/wave contiguous nontemporal stores.
    {
        v4f* fA = (v4f*)bufA;
        v4f* fB = (v4f*)bufB;
        const int wsel = (t >> 2) & 3;
        __syncthreads();                            // T_BC reads done
        #pragma unroll
        for (int rr = 0; rr < 2; ++rr) {
            v4f* f = rr ? fB : fA;
            #pragma unroll
            for (int q = 0; q < 4; ++q) {
                v4f s4;
                s4.x = v[rr][4 * q + 0]; s4.y = v[rr][4 * q + 1];
                s4.z = v[rr][4 * q + 2]; s4.w = v[rr][4 * q + 3];
                f[4 * t + (q ^ wsel)] = s4;
            }
        }
        __syncthreads();
        #pragma unroll
        for (int rr = 0; rr < 2; ++rr) {
            v4f* f = rr ? fB : fA;
            float* orow = out + (size_t)(row0 + rr) * N;
            #pragma unroll
            for (int k = 0; k < 4; ++k) {
                const int j = k * 256 + t;
                v4f s4 = f[(j & ~3) | ((j & 3) ^ ((j >> 4) & 3))];
                __builtin_nontemporal_store(s4, (v4f*)orow + j);
            }
        }
    }
}

// ---- Fallback (R6 structure) if workspace too small for the prepass
#define PAD_STRIDE 264
#define BUF_WORDS (16 * PAD_STRIDE)

__device__ __forceinline__ void layer16(float (&v)[4][16], const float4 (&w)[8], const int bit) {
    const int d = 1 << bit;
    #pragma unroll
    for (int pc = 0; pc < 8; ++pc) {
        const int lo = ((pc >> bit) << (bit + 1)) | (pc & (d - 1));
        const int hi = lo + d;
        #pragma unroll
        for (int r = 0; r < 4; ++r) {
            const float top = v[r][lo], bot = v[r][hi];
            v[r][lo] = w[pc].x * top + w[pc].y * bot;
            v[r][hi] = w[pc].z * top + w[pc].w * bot;
        }
    }
}

__global__ __launch_bounds__(256, 3)
void butterfly_kernel_fb(const float* __restrict__ x,
                         const float* __restrict__ tw,
                         float* __restrict__ out) {
    __shared__ float lds[BUF_WORDS];
    const int t = threadIdx.x;
    const int thi = t >> 4, tlo = t & 15;
    const int row0 = blockIdx.x * 4;
    const float4* tw4 = (const float4*)tw;
    float v[4][16];
    #pragma unroll
    for (int r = 0; r < 4; ++r) {
        const float* xr = x + (size_t)(row0 + r) * N + t;
        #pragma unroll
        for (int a = 0; a < 16; ++a) v[r][a] = __builtin_nontemporal_load(xr + a * 256);
    }
    #pragma unroll
    for (int l = 0; l < 4; ++l) {
        float4 w[8];
        #pragma unroll
        for (int pc = 0; pc < 8; ++pc) w[pc] = tw4[l * 2048 + pc * 256 + t];
        layer16(v, w, 3 - l);
    }
    #pragma unroll
    for (int r = 0; r < 4; ++r) {
        #pragma unroll
        for (int a = 0; a < 16; ++a) lds[a * PAD_STRIDE + t] = v[r][a];
        __syncthreads();
        #pragma unroll
        for (int b = 0; b < 16; ++b) v[r][b] = lds[thi * PAD_STRIDE + b * 16 + tlo];
        __syncthreads();
    }
    #pragma unroll
    for (int l = 4; l < 8; ++l) {
        float4 w[8];
        #pragma unroll
        for (int pc = 0; pc < 8; ++pc) w[pc] = tw4[l * 2048 + thi * 128 + pc * 16 + tlo];
        layer16(v, w, 3 - (l - 4));
    }
    #pragma unroll
    for (int r = 0; r < 4; ++r) {
        #pragma unroll
        for (int b = 0; b < 16; ++b) lds[thi * PAD_STRIDE + b * 16 + tlo] = v[r][b];
        __syncthreads();
        const float* bp = &lds[thi * PAD_STRIDE + tlo * 16];
        #pragma unroll
        for (int q = 0; q < 4; ++q) {
            v4f c4 = *(const v4f*)(bp + 4 * q);
            v[r][4 * q + 0] = c4.x; v[r][4 * q + 1] = c4.y;
            v[r][4 * q + 2] = c4.z; v[r][4 * q + 3] = c4.w;
        }
        if (r != 3) __syncthreads();
    }
    #pragma unroll
    for (int l = 8; l < 12; ++l) {
        float4 w[8];
        #pragma unroll
        for (int pc = 0; pc < 8; ++pc) w[pc] = tw4[l * 2048 + thi * 128 + tlo * 8 + pc];
        layer16(v, w, 3 - (l - 8));
    }
    #pragma unroll
    for (int r = 0; r < 4; ++r) {
        float* orow = out + (size_t)(row0 + r) * N + 16 * t;
        #pragma unroll
        for (int q = 0; q < 4; ++q) {
            v4f s4;
            s4.x = v[r][4 * q + 0]; s4.y = v[r][4 * q + 1];
            s4.z = v[r][4 * q + 2]; s4.w = v[r][4 * q + 3];
            *(v4f*)(orow + 4 * q) = s4;
        }
    }
}

extern "C" void kernel_launch(void* const* d_in, const int* in_sizes, int n_in,
                              void* d_out, int out_size, void* d_ws, size_t ws_size,
                              hipStream_t stream) {
    const float* x  = (const float*)d_in[0];
    const float* tw = (const float*)d_in[1];
    float* out      = (float*)d_out;
    dim3 block(256);
    if (ws_size >= (size_t)NWS_F4 * 16u) {
        float4* nws = (float4*)d_ws;
        hipLaunchKernelGGL(permute_tw_kernel, dim3(64), block, 0, stream, tw, nws);
        hipLaunchKernelGGL(butterfly_kernel, dim3(BATCH / ROWS), block, 0, stream,
                           x, tw, nws, out);
    } else {
        hipLaunchKernelGGL(butterfly_kernel_fb, dim3(BATCH / 4), block, 0, stream,
                           x, tw, out);
    }
}

// Round 18
// 65.015 us; speedup vs baseline: 1.1916x; 1.1916x over previous
//
#include <hip/hip_runtime.h>

#define ROWS 4
#define N 4096
#define BATCH 8192
#define S_AB 264            // arena row stride (floats): 256+8
#define ARENA 4224          // floats per arena (16*264); 2 arenas = 33792 B
#define NWS_F4 (8 * 2048)   // permuted f32 twiddles, layers 4..11

typedef float v4f __attribute__((ext_vector_type(4)));

// Half-layer butterfly: pcs [pcb, pcb+4) with twiddles in s[0..3] (R8-verified).
__device__ __forceinline__ void half_layer(float (&v)[ROWS][16],
                                           const float4 (&s)[4],
                                           const int bit, const int pcb) {
    const int d = 1 << bit;
    #pragma unroll
    for (int i = 0; i < 4; ++i) {
        const int pc = pcb + i;
        const int lo = ((pc >> bit) << (bit + 1)) | (pc & (d - 1));
        const int hi = lo + d;
        #pragma unroll
        for (int r = 0; r < ROWS; ++r) {
            const float top = v[r][lo], bot = v[r][hi];
            v[r][lo] = s[i].x * top + s[i].y * bot;
            v[r][hi] = s[i].z * top + s[i].w * bot;
        }
    }
}

// ---- Prepass (f32): layers 4..11 -> lane-coalesced nws.
__global__ __launch_bounds__(256)
void permute_tw_kernel(const float* __restrict__ tw, float4* __restrict__ nws) {
    const int i = blockIdx.x * 256 + threadIdx.x;   // 0 .. 16383
    const int s  = i >> 11;                         // slot 0..7 -> layer 4+s
    const int j  = i & 2047;
    const int pc = j >> 8;
    const int a  = (j >> 4) & 15;
    const int cb = j & 15;
    const float4* tw4 = (const float4*)tw;
    const int src = (s < 4) ? (a * 128 + pc * 16 + cb)   // stage B layers 4..7
                            : (a * 128 + cb * 8 + pc);   // stage C layers 8..11
    nws[i] = tw4[(4 + s) * 2048 + src];
}

// R16 champion (64.65us), restored after R17's ROWS=2 falsification.
// Structure bounded by falsification on every axis: ROWS {2:77us, 4:best,
// 8:122us}; store restage load-bearing (R14: removing +24us); f16 twiddles
// regressed (R15); 3-slot prefetch +3% (kept); conflicts/barriers/occupancy
// knobs all null. Balanced regime: HBM ~50%, L2 ~48%, LDS ~40%, VALU ~23%.
__global__ __launch_bounds__(256, 2)
void butterfly_kernel(const float* __restrict__ x,
                      const float* __restrict__ tw,
                      const float4* __restrict__ nws,
                      float* __restrict__ out) {
    __shared__ float lds[2 * ARENA];
    float* bufA = lds;
    float* bufB = lds + ARENA;
    const int t   = threadIdx.x;
    const int thi = t >> 4;
    const int tlo = t & 15;
    const int row0 = blockIdx.x * ROWS;
    const float4* tw4 = (const float4*)tw;

    auto ldA = [&](int l, int pcb, float4 (&s)[4]) {     // stage A natural (coalesced)
        #pragma unroll
        for (int i = 0; i < 4; ++i) s[i] = tw4[l * 2048 + (pcb + i) * 256 + t];
    };
    auto ldN = [&](int l, int pcb, float4 (&s)[4]) {     // layers 4..11 via nws
        #pragma unroll
        for (int i = 0; i < 4; ++i) s[i] = nws[(l - 4) * 2048 + (pcb + i) * 256 + t];
    };

    float v[ROWS][16];
    float4 S0[4], S1[4], S2[4];

    // ---- Stage-in: 16 dwordx4/thread through linear LDS; rows 2/3 loads +
    // layer-0 twiddle prefetch fly over the stage-in barriers.
    {
        const float* r0 = x + (size_t)(row0 + 0) * N + 4 * t;
        const float* r1 = x + (size_t)(row0 + 1) * N + 4 * t;
        const float* r2 = x + (size_t)(row0 + 2) * N + 4 * t;
        const float* r3 = x + (size_t)(row0 + 3) * N + 4 * t;
        v4f t0[4], t1[4];
        #pragma unroll
        for (int i = 0; i < 4; ++i) t0[i] = *(const v4f*)(r0 + i * 1024);
        #pragma unroll
        for (int i = 0; i < 4; ++i) t1[i] = *(const v4f*)(r1 + i * 1024);
        #pragma unroll
        for (int i = 0; i < 4; ++i) *(v4f*)(bufA + i * 1024 + 4 * t) = t0[i];
        #pragma unroll
        for (int i = 0; i < 4; ++i) *(v4f*)(bufB + i * 1024 + 4 * t) = t1[i];
        #pragma unroll
        for (int i = 0; i < 4; ++i) t0[i] = *(const v4f*)(r2 + i * 1024);  // in flight
        #pragma unroll
        for (int i = 0; i < 4; ++i) t1[i] = *(const v4f*)(r3 + i * 1024);  // across bars
        __syncthreads();
        #pragma unroll
        for (int a = 0; a < 16; ++a) v[0][a] = bufA[a * 256 + t];   // stride-1: free
        #pragma unroll
        for (int a = 0; a < 16; ++a) v[1][a] = bufB[a * 256 + t];
        __syncthreads();
        #pragma unroll
        for (int i = 0; i < 4; ++i) *(v4f*)(bufA + i * 1024 + 4 * t) = t0[i];
        #pragma unroll
        for (int i = 0; i < 4; ++i) *(v4f*)(bufB + i * 1024 + 4 * t) = t1[i];
        ldA(0, 0, S0);                               // l0 twiddles fly over barrier
        ldA(0, 4, S1);
        __syncthreads();
        #pragma unroll
        for (int a = 0; a < 16; ++a) v[2][a] = bufA[a * 256 + t];
        #pragma unroll
        for (int a = 0; a < 16; ++a) v[3][a] = bufB[a * 256 + t];
    }

    // ---- Stage A: layers 0..3 (pairs in a), 3-slot pipeline: per layer
    // {load next.h0 -> free slot; compute cur.h0; load next.h1; compute cur.h1}
    ldA(1, 0, S2); half_layer(v, S0, 3, 0); ldA(1, 4, S0); half_layer(v, S1, 3, 4); // l=0
    ldA(2, 0, S1); half_layer(v, S2, 2, 0); ldA(2, 4, S2); half_layer(v, S0, 2, 4); // l=1
    ldA(3, 0, S0); half_layer(v, S1, 1, 0); ldA(3, 4, S1); half_layer(v, S2, 1, 4); // l=2
    ldN(4, 0, S2); half_layer(v, S0, 0, 0); ldN(4, 4, S0); half_layer(v, S1, 0, 4); // l=3; l4 flies over T_AB

    // ---- Transpose A->B, 2-row batches (write stride-1, read 2-way: free)
    __syncthreads();                                // stage-in reads complete
    #pragma unroll
    for (int a = 0; a < 16; ++a) bufA[a * S_AB + t] = v[0][a];
    #pragma unroll
    for (int a = 0; a < 16; ++a) bufB[a * S_AB + t] = v[1][a];
    __syncthreads();
    #pragma unroll
    for (int b = 0; b < 16; ++b) v[0][b] = bufA[thi * S_AB + b * 16 + tlo];
    #pragma unroll
    for (int b = 0; b < 16; ++b) v[1][b] = bufB[thi * S_AB + b * 16 + tlo];
    __syncthreads();
    #pragma unroll
    for (int a = 0; a < 16; ++a) bufA[a * S_AB + t] = v[2][a];
    #pragma unroll
    for (int a = 0; a < 16; ++a) bufB[a * S_AB + t] = v[3][a];
    __syncthreads();
    #pragma unroll
    for (int b = 0; b < 16; ++b) v[2][b] = bufA[thi * S_AB + b * 16 + tlo];
    #pragma unroll
    for (int b = 0; b < 16; ++b) v[3][b] = bufB[thi * S_AB + b * 16 + tlo];

    // ---- Stage B: layers 4..7 (pairs in b); S2=l4.h0, S0=l4.h1 already here
    ldN(5, 0, S1); half_layer(v, S2, 3, 0); ldN(5, 4, S2); half_layer(v, S0, 3, 4); // l=4
    ldN(6, 0, S0); half_layer(v, S1, 2, 0); ldN(6, 4, S1); half_layer(v, S2, 2, 4); // l=5
    ldN(7, 0, S2); half_layer(v, S0, 1, 0); ldN(7, 4, S0); half_layer(v, S1, 1, 4); // l=6
    ldN(8, 0, S1); half_layer(v, S2, 0, 0); ldN(8, 4, S2); half_layer(v, S0, 0, 4); // l=7; l8 flies over T_BC

    // ---- Transpose B->C, compact q-XOR layout (R12): elem (a,b,c) at
    // a*264 + b*16 + 4*((c>>2)^(b&3)) + (c&3).
    {
        __syncthreads();                            // T_AB reads done
        #pragma unroll
        for (int b = 0; b < 16; ++b) {
            const int coff = 4 * (((tlo >> 2) ^ (b & 3))) + (tlo & 3);
            bufA[thi * S_AB + b * 16 + coff] = v[0][b];
            bufB[thi * S_AB + b * 16 + coff] = v[1][b];
        }
        __syncthreads();
        #pragma unroll
        for (int rr = 0; rr < 2; ++rr) {
            const float* bp = (rr ? bufB : bufA) + thi * S_AB + tlo * 16;
            #pragma unroll
            for (int q = 0; q < 4; ++q) {
                v4f c4 = *(const v4f*)(bp + 4 * (q ^ (tlo & 3)));
                v[rr][4 * q + 0] = c4.x; v[rr][4 * q + 1] = c4.y;
                v[rr][4 * q + 2] = c4.z; v[rr][4 * q + 3] = c4.w;
            }
        }
        __syncthreads();
        #pragma unroll
        for (int b = 0; b < 16; ++b) {
            const int coff = 4 * (((tlo >> 2) ^ (b & 3))) + (tlo & 3);
            bufA[thi * S_AB + b * 16 + coff] = v[2][b];
            bufB[thi * S_AB + b * 16 + coff] = v[3][b];
        }
        __syncthreads();
        #pragma unroll
        for (int rr = 2; rr < 4; ++rr) {
            const float* bp = (rr == 3 ? bufB : bufA) + thi * S_AB + tlo * 16;
            #pragma unroll
            for (int q = 0; q < 4; ++q) {
                v4f c4 = *(const v4f*)(bp + 4 * (q ^ (tlo & 3)));
                v[rr][4 * q + 0] = c4.x; v[rr][4 * q + 1] = c4.y;
                v[rr][4 * q + 2] = c4.z; v[rr][4 * q + 3] = c4.w;
            }
        }
    }

    // ---- Stage C: layers 8..11 (pairs in c); S1=l8.h0, S2=l8.h1 already here
    ldN(9,  0, S0); half_layer(v, S1, 3, 0); ldN(9,  4, S1); half_layer(v, S2, 3, 4); // l=8
    ldN(10, 0, S2); half_layer(v, S0, 2, 0); ldN(10, 4, S0); half_layer(v, S1, 2, 4); // l=9
    ldN(11, 0, S1); half_layer(v, S2, 1, 0); ldN(11, 4, S2); half_layer(v, S0, 1, 4); // l=10
                    half_layer(v, S1, 0, 0);                 half_layer(v, S2, 0, 4); // l=11

    // ---- Store restage (load-bearing, R14): XOR layout, then 1KB/wave
    // contiguous nontemporal stores.
    {
        v4f* fA = (v4f*)bufA;
        v4f* fB = (v4f*)bufB;
        const int wsel = (t >> 2) & 3;
        __syncthreads();                            // T_BC reads done
        #pragma unroll
        for (int h = 0; h < 2; ++h) {
            #pragma unroll
            for (int rr = 0; rr < 2; ++rr) {
                v4f* f = rr ? fB : fA;
                const int r = 2 * h + rr;
                #pragma unroll
                for (int q = 0; q < 4; ++q) {
                    v4f s4;
                    s4.x = v[r][4 * q + 0]; s4.y = v[r][4 * q + 1];
                    s4.z = v[r][4 * q + 2]; s4.w = v[r][4 * q + 3];
                    f[4 * t + (q ^ wsel)] = s4;
                }
            }
            __syncthreads();
            #pragma unroll
            for (int rr = 0; rr < 2; ++rr) {
                v4f* f = rr ? fB : fA;
                const int r = 2 * h + rr;
                float* orow = out + (size_t)(row0 + r) * N;
                #pragma unroll
                for (int k = 0; k < 4; ++k) {
                    const int j = k * 256 + t;
                    v4f s4 = f[(j & ~3) | ((j & 3) ^ ((j >> 4) & 3))];
                    __builtin_nontemporal_store(s4, (v4f*)orow + j);
                }
            }
            if (h == 0) __syncthreads();
        }
    }
}

// ---- Fallback (R6 structure) if workspace too small for the prepass
#define PAD_STRIDE 264
#define BUF_WORDS (16 * PAD_STRIDE)

__device__ __forceinline__ void layer16(float (&v)[4][16], const float4 (&w)[8], const int bit) {
    const int d = 1 << bit;
    #pragma unroll
    for (int pc = 0; pc < 8; ++pc) {
        const int lo = ((pc >> bit) << (bit + 1)) | (pc & (d - 1));
        const int hi = lo + d;
        #pragma unroll
        for (int r = 0; r < 4; ++r) {
            const float top = v[r][lo], bot = v[r][hi];
            v[r][lo] = w[pc].x * top + w[pc].y * bot;
            v[r][hi] = w[pc].z * top + w[pc].w * bot;
        }
    }
}

__global__ __launch_bounds__(256, 3)
void butterfly_kernel_fb(const float* __restrict__ x,
                         const float* __restrict__ tw,
                         float* __restrict__ out) {
    __shared__ float lds[BUF_WORDS];
    const int t = threadIdx.x;
    const int thi = t >> 4, tlo = t & 15;
    const int row0 = blockIdx.x * 4;
    const float4* tw4 = (const float4*)tw;
    float v[4][16];
    #pragma unroll
    for (int r = 0; r < 4; ++r) {
        const float* xr = x + (size_t)(row0 + r) * N + t;
        #pragma unroll
        for (int a = 0; a < 16; ++a) v[r][a] = __builtin_nontemporal_load(xr + a * 256);
    }
    #pragma unroll
    for (int l = 0; l < 4; ++l) {
        float4 w[8];
        #pragma unroll
        for (int pc = 0; pc < 8; ++pc) w[pc] = tw4[l * 2048 + pc * 256 + t];
        layer16(v, w, 3 - l);
    }
    #pragma unroll
    for (int r = 0; r < 4; ++r) {
        #pragma unroll
        for (int a = 0; a < 16; ++a) lds[a * PAD_STRIDE + t] = v[r][a];
        __syncthreads();
        #pragma unroll
        for (int b = 0; b < 16; ++b) v[r][b] = lds[thi * PAD_STRIDE + b * 16 + tlo];
        __syncthreads();
    }
    #pragma unroll
    for (int l = 4; l < 8; ++l) {
        float4 w[8];
        #pragma unroll
        for (int pc = 0; pc < 8; ++pc) w[pc] = tw4[l * 2048 + thi * 128 + pc * 16 + tlo];
        layer16(v, w, 3 - (l - 4));
    }
    #pragma unroll
    for (int r = 0; r < 4; ++r) {
        #pragma unroll
        for (int b = 0; b < 16; ++b) lds[thi * PAD_STRIDE + b * 16 + tlo] = v[r][b];
        __syncthreads();
        const float* bp = &lds[thi * PAD_STRIDE + tlo * 16];
        #pragma unroll
        for (int q = 0; q < 4; ++q) {
            v4f c4 = *(const v4f*)(bp + 4 * q);
            v[r][4 * q + 0] = c4.x; v[r][4 * q + 1] = c4.y;
            v[r][4 * q + 2] = c4.z; v[r][4 * q + 3] = c4.w;
        }
        if (r != 3) __syncthreads();
    }
    #pragma unroll
    for (int l = 8; l < 12; ++l) {
        float4 w[8];
        #pragma unroll
        for (int pc = 0; pc < 8; ++pc) w[pc] = tw4[l * 2048 + thi * 128 + tlo * 8 + pc];
        layer16(v, w, 3 - (l - 8));
    }
    #pragma unroll
    for (int r = 0; r < 4; ++r) {
        float* orow = out + (size_t)(row0 + r) * N + 16 * t;
        #pragma unroll
        for (int q = 0; q < 4; ++q) {
            v4f s4;
            s4.x = v[r][4 * q + 0]; s4.y = v[r][4 * q + 1];
            s4.z = v[r][4 * q + 2]; s4.w = v[r][4 * q + 3];
            *(v4f*)(orow + 4 * q) = s4;
        }
    }
}

extern "C" void kernel_launch(void* const* d_in, const int* in_sizes, int n_in,
                              void* d_out, int out_size, void* d_ws, size_t ws_size,
                              hipStream_t stream) {
    const float* x  = (const float*)d_in[0];
    const float* tw = (const float*)d_in[1];
    float* out      = (float*)d_out;
    dim3 block(256);
    if (ws_size >= (size_t)NWS_F4 * 16u) {
        float4* nws = (float4*)d_ws;
        hipLaunchKernelGGL(permute_tw_kernel, dim3(64), block, 0, stream, tw, nws);
        hipLaunchKernelGGL(butterfly_kernel, dim3(BATCH / ROWS), block, 0, stream,
                           x, tw, nws, out);
    } else {
        hipLaunchKernelGGL(butterfly_kernel_fb, dim3(BATCH / 4), block, 0, stream,
                           x, tw, out);
    }
}